// Round 2
// baseline (989.388 us; speedup 1.0000x reference)
//
#include <hip/hip_runtime.h>
#include <cstdint>

#define D_MODEL 1024
#define N_EXP   16
#define D_FF    4096
#define NTOK    4096      // B*T
#define NSEL    8192      // NTOK * k

typedef uint16_t u16;
typedef __bf16    bf16x8 __attribute__((ext_vector_type(8)));
typedef uint16_t  u16x8  __attribute__((ext_vector_type(8)));
typedef float     f32x4  __attribute__((ext_vector_type(4)));

__device__ __forceinline__ u16 f2bf(float x) {
    union { float f; uint32_t i; } c; c.f = x;
    uint32_t i = c.i + 0x7fffu + ((c.i >> 16) & 1u);   // RNE (finite data)
    return (u16)(i >> 16);
}

// async global->LDS, 16B per lane; lds base must be wave-uniform
#define ASYNC16(gp, lp) __builtin_amdgcn_global_load_lds( \
    (__attribute__((address_space(1))) void*)(gp),        \
    (__attribute__((address_space(3))) void*)(lp), 16, 0, 0)

// ---------------- gating: one wave per token, exact fp32 ----------------
__global__ void gate_kernel(const float* __restrict__ x, const float* __restrict__ Wg,
                            int* __restrict__ tok_idx, float* __restrict__ tok_w,
                            int* __restrict__ counts)
{
    const int lane = threadIdx.x & 63;
    const int t = blockIdx.x * 4 + (threadIdx.x >> 6);
    const float* xr = x + (size_t)t * D_MODEL;
    float acc[N_EXP];
    #pragma unroll
    for (int e = 0; e < N_EXP; e++) acc[e] = 0.f;
    for (int d = lane; d < D_MODEL; d += 64) {
        float xv = xr[d];
        const float* wr = Wg + d * N_EXP;
        #pragma unroll
        for (int e = 0; e < N_EXP; e++) acc[e] += xv * wr[e];
    }
    #pragma unroll
    for (int e = 0; e < N_EXP; e++) {
        float v = acc[e];
        #pragma unroll
        for (int o = 32; o > 0; o >>= 1) v += __shfl_xor(v, o, 64);
        acc[e] = v;
    }
    if (lane == 0) {
        int i0 = 0; float v0 = acc[0];
        #pragma unroll
        for (int e = 1; e < N_EXP; e++) if (acc[e] > v0) { v0 = acc[e]; i0 = e; }
        int i1 = (i0 == 0) ? 1 : 0; float v1 = -3.0e38f;
        #pragma unroll
        for (int e = 0; e < N_EXP; e++) if (e != i0 && acc[e] > v1) { v1 = acc[e]; i1 = e; }
        float e1  = __expf(v1 - v0);
        float inv = 1.f / (1.f + e1);
        tok_idx[2 * t] = i0;  tok_idx[2 * t + 1] = i1;
        tok_w[2 * t] = inv;   tok_w[2 * t + 1] = e1 * inv;
        atomicAdd(&counts[i0], 1);
        atomicAdd(&counts[i1], 1);
    }
}

__global__ void scan_kernel(const int* __restrict__ counts, int* __restrict__ offsets,
                            int* __restrict__ cursors)
{
    if (threadIdx.x == 0) {
        int s = 0;
        #pragma unroll
        for (int e = 0; e < N_EXP; e++) { offsets[e] = s; cursors[e] = s; s += counts[e]; }
        offsets[N_EXP] = s;   // == NSEL
    }
}

__global__ void scatter_kernel(const int* __restrict__ tok_idx, const float* __restrict__ tok_w,
                               int* __restrict__ cursors, int* __restrict__ perm_token,
                               float* __restrict__ perm_w, int* __restrict__ slots)
{
    const int t = blockIdx.x * 256 + threadIdx.x;
    #pragma unroll
    for (int j = 0; j < 2; j++) {
        int e = tok_idx[2 * t + j];
        int slot = atomicAdd(&cursors[e], 1);
        perm_token[slot] = t;
        perm_w[slot] = tok_w[2 * t + j];
        slots[2 * t + j] = slot;
    }
}

// ---------------- grouped GEMM, 128x128 tile, BK=32, 4 waves ----------------
// AFP32: A is fp32 (x), staged via f32x4 load + convert + ds_write_b128.
//        else A is bf16 (h), staged via global_load_lds width=16.
// W is fp32 [e][K][N] (k-major); converted + transposed into LDS [n][k]
// with XOR granule swizzle (granule = 8 u16 along k).
template<bool AFP32, bool GATHER, bool SWISH>
__global__ __launch_bounds__(256, 3)
void gemm_kernel(const void* __restrict__ Av, const float* __restrict__ W,
                 const float* __restrict__ bias, const int* __restrict__ offsets,
                 const int* __restrict__ perm_token, const float* __restrict__ perm_w,
                 u16* __restrict__ Hout, float* __restrict__ Yout,
                 int K, int N)
{
    const int e   = blockIdx.z;
    const int off = offsets[e];
    const int cnt = offsets[e + 1] - off;
    const int m0  = blockIdx.y * 128;
    if (m0 >= cnt) return;
    const int n0  = blockIdx.x * 128;

    __shared__ u16 Alds[128 * 32];   // [m][k] row-major
    __shared__ u16 Blds[128 * 32];   // [n][k] transposed, granule-swizzled

    const int tid  = threadIdx.x;
    const int lane = tid & 63;
    const int w    = tid >> 6;
    const int wm   = w & 1;
    const int wn   = w >> 1;

    // --- A staging setup ---
    const float* apf0 = nullptr; const float* apf1 = nullptr; int ar0 = 0, akj = 0;
    const u16*   aph0 = nullptr; const u16*   aph1 = nullptr;
    if constexpr (AFP32) {
        akj = tid & 3;                 // k-octet
        ar0 = tid >> 2;                // row 0..63 (and +64)
        int rA = m0 + ar0;       if (rA > cnt - 1) rA = cnt - 1;
        int rB = m0 + ar0 + 64;  if (rB > cnt - 1) rB = cnt - 1;
        const int sA = GATHER ? perm_token[off + rA] : (off + rA);
        const int sB = GATHER ? perm_token[off + rB] : (off + rB);
        apf0 = (const float*)Av + (size_t)sA * K + akj * 8;
        apf1 = (const float*)Av + (size_t)sB * K + akj * 8;
    } else {
        const int arow0 = w * 16 + (lane >> 2);
        const int acol  = (lane & 3) * 8;
        int rA = m0 + arow0;      if (rA > cnt - 1) rA = cnt - 1;
        int rB = m0 + arow0 + 64; if (rB > cnt - 1) rB = cnt - 1;
        const int sA = GATHER ? perm_token[off + rA] : (off + rA);
        const int sB = GATHER ? perm_token[off + rB] : (off + rB);
        aph0 = (const u16*)Av + (size_t)sA * K + acol;
        aph1 = (const u16*)Av + (size_t)sB * K + acol;
    }

    // --- B staging setup: thread handles (fo, d0) and (fo, d0+16) ---
    const int fo = tid & 15;        // n-octet (8 consecutive n)
    const int d0 = tid >> 4;        // k-row 0..15
    const int d1 = d0 + 16;
    const float* bbase = W + (size_t)e * K * N + n0 + fo * 8;
    const int bl0 = (((d0 >> 3) ^ (fo & 3)) * 8) + (d0 & 7);
    const int bl1 = (((d1 >> 3) ^ (fo & 3)) * 8) + (d1 & 7);

    // --- fragment read bases ---
    const int q     = lane >> 4;
    const int a_rd  = (wm * 64 + (lane & 15)) * 32 + q * 8;
    const int fbase = wn * 64 + (lane & 15);
    int b_rd[4];
    #pragma unroll
    for (int ni = 0; ni < 4; ni++) {
        int f = fbase + ni * 16;
        int g = q ^ ((f >> 3) & 3);
        b_rd[ni] = f * 32 + g * 8;
    }

    f32x4 acc[4][4] = {};

    for (int kt = 0; kt < K; kt += 32) {
        // A tile
        if constexpr (AFP32) {
            f32x4 a0 = *(const f32x4*)(apf0 + kt);
            f32x4 a1 = *(const f32x4*)(apf0 + kt + 4);
            f32x4 c0 = *(const f32x4*)(apf1 + kt);
            f32x4 c1 = *(const f32x4*)(apf1 + kt + 4);
            u16x8 pa, pb;
            #pragma unroll
            for (int i = 0; i < 4; i++) { pa[i] = f2bf(a0[i]); pa[4 + i] = f2bf(a1[i]); }
            #pragma unroll
            for (int i = 0; i < 4; i++) { pb[i] = f2bf(c0[i]); pb[4 + i] = f2bf(c1[i]); }
            *(u16x8*)(&Alds[ar0 * 32 + akj * 8])        = pa;
            *(u16x8*)(&Alds[(ar0 + 64) * 32 + akj * 8]) = pb;
        } else {
            ASYNC16(aph0 + kt, &Alds[w * 512]);
            ASYNC16(aph1 + kt, &Alds[(w + 4) * 512]);
        }
        // B tile: convert + transpose
        {
            const float* bp = bbase + (size_t)kt * N;
            f32x4 w00 = *(const f32x4*)(bp + (size_t)d0 * N);
            f32x4 w01 = *(const f32x4*)(bp + (size_t)d0 * N + 4);
            f32x4 w10 = *(const f32x4*)(bp + (size_t)d1 * N);
            f32x4 w11 = *(const f32x4*)(bp + (size_t)d1 * N + 4);
            #pragma unroll
            for (int j = 0; j < 4; j++) Blds[(fo * 8 + j) * 32 + bl0]     = f2bf(w00[j]);
            #pragma unroll
            for (int j = 0; j < 4; j++) Blds[(fo * 8 + 4 + j) * 32 + bl0] = f2bf(w01[j]);
            #pragma unroll
            for (int j = 0; j < 4; j++) Blds[(fo * 8 + j) * 32 + bl1]     = f2bf(w10[j]);
            #pragma unroll
            for (int j = 0; j < 4; j++) Blds[(fo * 8 + 4 + j) * 32 + bl1] = f2bf(w11[j]);
        }
        __syncthreads();

        u16x8 af[4], bfr[4];
        #pragma unroll
        for (int mi = 0; mi < 4; mi++) af[mi] = *(const u16x8*)(&Alds[a_rd + mi * 16 * 32]);
        #pragma unroll
        for (int ni = 0; ni < 4; ni++) bfr[ni] = *(const u16x8*)(&Blds[b_rd[ni]]);
        #pragma unroll
        for (int mi = 0; mi < 4; mi++)
            #pragma unroll
            for (int ni = 0; ni < 4; ni++)
                acc[mi][ni] = __builtin_amdgcn_mfma_f32_16x16x32_bf16(
                    __builtin_bit_cast(bf16x8, af[mi]),
                    __builtin_bit_cast(bf16x8, bfr[ni]),
                    acc[mi][ni], 0, 0, 0);
        __syncthreads();
    }

    // epilogue: C/D layout col=lane&15, row=(lane>>4)*4+reg  [m89-verified]
    const int rowq = (lane >> 4) * 4;
    #pragma unroll
    for (int mi = 0; mi < 4; mi++) {
        #pragma unroll
        for (int r = 0; r < 4; r++) {
            const int m = m0 + wm * 64 + mi * 16 + rowq + r;
            if (m < cnt) {
                const size_t gm = (size_t)(off + m);
                float pw = SWISH ? 0.f : perm_w[gm];
                #pragma unroll
                for (int ni = 0; ni < 4; ni++) {
                    const int gn = n0 + fbase + ni * 16;
                    float c = acc[mi][ni][r] + bias[(size_t)e * N + gn];
                    if (SWISH) {
                        float s = c / (1.f + __expf(-c));   // swish
                        Hout[gm * (size_t)N + gn] = f2bf(s);
                    } else {
                        Yout[gm * (size_t)N + gn] = c * pw;
                    }
                }
            }
        }
    }
}

// ---------------- combine: out[t] = Y[slot0] + Y[slot1] (fp32 out) ----------------
__global__ void combine_kernel(const float* __restrict__ Y, const int* __restrict__ slots,
                               float* __restrict__ out)
{
    const int idx = blockIdx.x * 256 + threadIdx.x;
    const int t = idx >> 8;
    const int d = (idx & 255) * 4;
    const int s0 = slots[2 * t], s1 = slots[2 * t + 1];
    f32x4 a = *(const f32x4*)(Y + (size_t)s0 * D_MODEL + d);
    f32x4 b = *(const f32x4*)(Y + (size_t)s1 * D_MODEL + d);
    f32x4 o = a + b;
    *(f32x4*)(out + (size_t)t * D_MODEL + d) = o;
}

extern "C" void kernel_launch(void* const* d_in, const int* in_sizes, int n_in,
                              void* d_out, int out_size, void* d_ws, size_t ws_size,
                              hipStream_t stream)
{
    const float* x  = (const float*)d_in[0];
    const float* W1 = (const float*)d_in[1];
    const float* b1 = (const float*)d_in[2];
    const float* W2 = (const float*)d_in[3];
    const float* b2 = (const float*)d_in[4];
    const float* Wg = (const float*)d_in[5];
    // d_in[6] = k (always 2)

    char* ws = (char*)d_ws;
    int*   counts     = (int*)(ws);                      // 64 B
    int*   offsets    = (int*)(ws + 64);                 // 17 ints
    int*   cursors    = (int*)(ws + 192);                // 16 ints
    int*   tok_idx    = (int*)(ws + 256);                // 8192 ints
    float* tok_w      = (float*)(ws + 256 + 32768);      // 8192 f32
    int*   slots      = (int*)(ws + 256 + 2 * 32768);    // 8192 ints
    int*   perm_token = (int*)(ws + 256 + 3 * 32768);    // 8192 ints
    float* perm_w     = (float*)(ws + 256 + 4 * 32768);  // 8192 f32
    u16*   h          = (u16*)(ws + 262144);                             // 64 MB bf16
    float* Yslot      = (float*)(ws + 262144 + (size_t)NSEL * D_FF * 2); // 32 MB f32
    // total ws needed ~= 96.3 MiB

    hipMemsetAsync(counts, 0, 64, stream);
    gate_kernel<<<dim3(NTOK / 4), dim3(256), 0, stream>>>(x, Wg, tok_idx, tok_w, counts);
    scan_kernel<<<dim3(1), dim3(64), 0, stream>>>(counts, offsets, cursors);
    scatter_kernel<<<dim3(NTOK / 256), dim3(256), 0, stream>>>(tok_idx, tok_w, cursors,
                                                               perm_token, perm_w, slots);
    gemm_kernel<true, true, true><<<dim3(32, 32, 16), dim3(256), 0, stream>>>(
        (const void*)x, W1, b1, offsets, perm_token, nullptr, h, nullptr, D_MODEL, D_FF);
    gemm_kernel<false, false, false><<<dim3(8, 32, 16), dim3(256), 0, stream>>>(
        (const void*)h, W2, b2, offsets, nullptr, perm_w, nullptr, Yslot, D_FF, D_MODEL);
    combine_kernel<<<dim3(NTOK), dim3(256), 0, stream>>>(Yslot, slots, (float*)d_out);
}